// Round 21
// baseline (83.537 us; speedup 1.0000x reference)
//
#include <hip/hip_runtime.h>
#include <hip/hip_bf16.h>
#include <stdint.h>

// Problem constants (B=4, T=2048, C=512, H=8, D=64)
constexpr int Bn = 4;
constexpr int Tn = 2048;
constexpr int Cn = 512;
constexpr int Hn = 8;
constexpr int Dn = 64;
constexpr int BT = Bn * Tn;          // 8192
constexpr int NQKV = 3 * Cn;         // 1536

typedef __attribute__((ext_vector_type(4))) float  f32x4;
typedef __attribute__((ext_vector_type(8))) short  s16x8;
typedef __attribute__((ext_vector_type(4))) short  s16x4;

__device__ __forceinline__ short f2bs(float f) {
    __hip_bfloat16 h = __float2bfloat16(f);
    return *reinterpret_cast<short*>(&h);
}

// async global->LDS, 16B per lane (linear LDS dest: wave base + lane*16)
__device__ __forceinline__ void gload16(const short* g, short* l) {
    __builtin_amdgcn_global_load_lds(
        (const __attribute__((address_space(1))) void*)g,
        (__attribute__((address_space(3))) void*)l, 16, 0, 0);
}

// ---------------- fused prep kernel ----------------
// blocks [0,4096): x fp32 -> bf16          (job A)
// blocks [4096,4352): weight transposes    (job B)
// blocks [4352,4864): rope cos/sin table   (job C)

__global__ __launch_bounds__(256) void k_prep(const float* __restrict__ x,
                                              const float* __restrict__ Wqkv,
                                              const float* __restrict__ Wproj,
                                              short* __restrict__ xb,
                                              short* __restrict__ wqkvT,
                                              short* __restrict__ wprojT,
                                              float2* __restrict__ csT) {
    const int bid = blockIdx.x;
    const int tid = threadIdx.x;
    __shared__ float lds[64 * 65];

    if (bid < 4096) {                        // A: conv x (float4 per thread)
        int i = bid * 256 + tid;
        f32x4 v = reinterpret_cast<const f32x4*>(x)[i];
        s16x4 o;
        o[0] = f2bs(v[0]); o[1] = f2bs(v[1]); o[2] = f2bs(v[2]); o[3] = f2bs(v[3]);
        reinterpret_cast<s16x4*>(xb)[i] = o;
    } else if (bid < 4352) {                 // B: weight transpose via LDS tile
        int wb = bid - 4096;
        const float* W; short* out; int N, n0, k0;
        if (wb < 192) {
            W = Wqkv; out = wqkvT; N = NQKV;
            n0 = (wb >> 3) * 64; k0 = (wb & 7) * 64;
        } else {
            wb -= 192;
            W = Wproj; out = wprojT; N = Cn;
            n0 = (wb >> 3) * 64; k0 = (wb & 7) * 64;
        }
#pragma unroll
        for (int i = 0; i < 16; ++i) {
            int flat = i * 256 + tid;
            int k = flat >> 6, n = flat & 63;
            lds[n * 65 + k] = W[(size_t)(k0 + k) * N + n0 + n];
        }
        __syncthreads();
#pragma unroll
        for (int i = 0; i < 16; ++i) {
            int flat = i * 256 + tid;
            int n = flat >> 6, k = flat & 63;
            out[(size_t)(n0 + n) * 512 + k0 + k] = f2bs(lds[n * 65 + k]);
        }
    } else {                                 // C: rope table
        int i = (bid - 4352) * 256 + tid;    // < T*D
        int t = i >> 6, d = i & 63;
        float inv = exp2f(-(float)(d & 31) * 0.41524101186f);
        float fr = (float)t * inv;
        csT[i] = make_float2(cosf(fr), sinf(fr));
    }
}

// ---------------- GEMM (128 x NT*32 tile, BK=32, counted vmcnt) ----------------
// r19 structure. NT = N-subtiles per wave (4 -> 128-wide tile, 2 -> 64-wide).
// MODE 0 (NT=4): RoPE epilogue, grid (12,64). MODE 1 (NT=2): fp32 store,
// grid (8,64) = 512 blocks = 2/CU (fixes gemm1's 1-block/CU under-residency).
// LDS: As 16KB dbuf + Bs NT*4KB dbuf. Counted vmcnt (loads/stage = 2+NT/2).

template <int MODE, int NT>
__global__ __launch_bounds__(256, 4) void gemm_kernel(
    const short* __restrict__ A, const short* __restrict__ Bt,
    const float2* __restrict__ csT,
    short* __restrict__ Qb, short* __restrict__ Kb, short* __restrict__ Vt,
    float* __restrict__ outF) {
    const int m0 = blockIdx.y * 128;
    const int n0 = blockIdx.x * (NT * 32);
    const int tid = threadIdx.x;
    const int w = tid >> 6, lane = tid & 63;
    const int qi = lane & 15, g = lane >> 4;
    const int wr = w >> 1, wc = w & 1;

    __shared__ short As[2][128 * 32];
    __shared__ short Bs[2][NT * 32 * 32];

    f32x4 acc[4][NT];
#pragma unroll
    for (int mt = 0; mt < 4; ++mt)
#pragma unroll
        for (int nt = 0; nt < NT; ++nt) acc[mt][nt] = (f32x4){0.f, 0.f, 0.f, 0.f};

    const int lrr = lane >> 2;          // sub-row within 16-row slab
    const int lp = lane & 3;            // stored chunk position

#define STAGEG(buf, k0)                                                         \
    {                                                                           \
        _Pragma("unroll")                                                       \
        for (int i_ = 0; i_ < 2; ++i_) {                                        \
            int row_ = i_ * 64 + w * 16 + lrr;                                  \
            int c_ = lp ^ ((row_ ^ (row_ >> 2)) & 3);                           \
            gload16(&A[(size_t)(m0 + row_) * 512 + (k0) + c_ * 8],              \
                    &As[buf][(i_ * 64 + w * 16) * 32 + lane * 8]);              \
            if (i_ < NT / 2)                                                    \
                gload16(&Bt[(size_t)(n0 + row_) * 512 + (k0) + c_ * 8],         \
                        &Bs[buf][(i_ * 64 + w * 16) * 32 + lane * 8]);          \
        }                                                                       \
    }

    STAGEG(0, 0);

    for (int it = 0; it < 16; ++it) {                // K = 16 * 32
        const int cur = it & 1;
        if (it + 1 < 16) {
            STAGEG((it + 1) & 1, (it + 1) * 32);
            if constexpr (NT == 4) {
                asm volatile("s_waitcnt vmcnt(4)" ::: "memory");
            } else {
                asm volatile("s_waitcnt vmcnt(3)" ::: "memory");
            }
        } else {
            asm volatile("s_waitcnt vmcnt(0)" ::: "memory");
        }
        __builtin_amdgcn_s_barrier();
        asm volatile("" ::: "memory");

        s16x8 af[4], bf[NT];
#pragma unroll
        for (int mt = 0; mt < 4; ++mt) {
            int row = wr * 64 + mt * 16 + qi;
            int p = g ^ ((row ^ (row >> 2)) & 3);
            af[mt] = *(const s16x8*)&As[cur][row * 32 + p * 8];
        }
#pragma unroll
        for (int nt = 0; nt < NT; ++nt) {
            int row = wc * (NT * 16) + nt * 16 + qi;
            int p = g ^ ((row ^ (row >> 2)) & 3);
            bf[nt] = *(const s16x8*)&Bs[cur][row * 32 + p * 8];
        }
#pragma unroll
        for (int mt = 0; mt < 4; ++mt)
#pragma unroll
            for (int nt = 0; nt < NT; ++nt)
                acc[mt][nt] = __builtin_amdgcn_mfma_f32_16x16x32_bf16(
                    af[mt], bf[nt], acc[mt][nt], 0, 0, 0);

        asm volatile("" ::: "memory");
        __builtin_amdgcn_s_barrier();
        asm volatile("" ::: "memory");
    }
#undef STAGEG

    if constexpr (MODE == 1) {
#pragma unroll
        for (int mt = 0; mt < 4; ++mt)
#pragma unroll
            for (int nt = 0; nt < NT; ++nt)
#pragma unroll
                for (int r = 0; r < 4; ++r)
                    outF[(size_t)(m0 + wr * 64 + mt * 16 + 4 * g + r) * 512 +
                         n0 + wc * (NT * 16) + nt * 16 + qi] = acc[mt][nt][r];
    } else {
        const int seg64 = (n0 >> 6) + wc;            // = h*3 + seg
        const int h = seg64 / 3;
        const int seg = seg64 % 3;                   // 0=q 1=k 2=v
        const int b = m0 >> 11;
        const int tb = (m0 & 2047) + wr * 64;
        const float QSC = 0.125f * 1.44269504f;      // pre-fold softmax scale into Q
        if (seg == 2) {
            // V transposed + fragment-permuted: Vt[bh][d][ (t&~31) + g2*8 + sub2*4 + r2 ]
            const size_t vbase = (size_t)(b * Hn + h) * Dn;
#pragma unroll
            for (int mt = 0; mt < 4; ++mt)
#pragma unroll
                for (int nt = 0; nt < NT; ++nt)
#pragma unroll
                    for (int r = 0; r < 4; ++r) {
                        int t = tb + mt * 16 + 4 * g + r;
                        int d = nt * 16 + qi;
                        int o = t & 31;
                        int jj = (t & ~31) + ((o >> 2) & 3) * 8 + (o >> 4) * 4 + (o & 3);
                        Vt[(vbase + d) * Tn + jj] = f2bs(acc[mt][nt][r]);
                    }
        } else {
            short* dst = (seg == 0) ? Qb : Kb;
            const float post = (seg == 0) ? QSC : 1.0f;
            const size_t headbase = (size_t)(b * Hn + h) * Tn;
#pragma unroll
            for (int mt = 0; mt < 4; ++mt)
#pragma unroll
                for (int nt = 0; nt < NT; ++nt)
#pragma unroll
                    for (int r = 0; r < 4; ++r) {
                        int t = tb + mt * 16 + 4 * g + r;
                        int d = nt * 16 + qi;
                        float val = acc[mt][nt][r];
                        float pv = (nt < NT / 2) ? -acc[mt][nt + NT / 2][r]
                                                 : acc[mt][nt - NT / 2][r];
                        float2 cs = csT[t * 64 + d];
                        dst[(headbase + t) * Dn + d] = f2bs((val * cs.x + pv * cs.y) * post);
                    }
        }
    }
}

// ---------------- causal flash attention (IN-BLOCK split-K, 8 waves) -----------
// (r18 structure verbatim — proven best of 6 attn variants)

__global__ __launch_bounds__(512, 4) void attn_kernel(const short* __restrict__ Qb,
                                                      const short* __restrict__ Kb,
                                                      const short* __restrict__ Vt,
                                                      short* __restrict__ AO) {
    const int idx = blockIdx.x;
    const int bh = idx & 31;
    const int qt = 31 - (idx >> 5);                  // heavy tiles dispatch first
    const int q0 = qt * 64;
    const int tid = threadIdx.x;
    const int w = tid >> 6, lane = tid & 63;
    const int qi = lane & 15, g = lane >> 4;
    const int grp = w >> 2;                          // chunk-range group
    const int wg = w & 3;                            // wave-in-group (16 rows)
    const int b = bh >> 3, h = bh & 7;

    __shared__ short Ks[2][2][64 * 64];  // [grp][dbuf][key][d]     32KB
    __shared__ short Vs[2][2][64 * 64];  // [grp][dbuf][d][key-perm] 32KB

    const short* Qh = Qb + (size_t)bh * Tn * Dn;
    const short* Kh = Kb + (size_t)bh * Tn * Dn;
    const short* Vh = Vt + (size_t)bh * Dn * Tn;

    const int wrow0 = q0 + wg * 16;      // wave's 16 query rows
    s16x8 qf[2];
#pragma unroll
    for (int dh = 0; dh < 2; ++dh)
        qf[dh] = *(const s16x8*)&Qh[(size_t)(wrow0 + qi) * Dn + dh * 32 + g * 8];

    f32x4 O[4];
#pragma unroll
    for (int dt = 0; dt < 4; ++dt) O[dt] = (f32x4){0.f, 0.f, 0.f, 0.f};
    float lsum = 0.f;

    const int nch = qt + 1;                          // 64-key chunks total
    const int mid = (nch + 1) >> 1;                  // group A: [0,mid)
    const int chbase = grp ? mid : 0;
    const int nmy = grp ? (nch - mid) : mid;         // my group's chunk count
    const f32x4 z4 = {0.f, 0.f, 0.f, 0.f};

    const int lr = lane >> 3;                        // staging sub-row
    const int lc = (lane & 7) ^ lr;                  // pre-swizzled global chunk

#define STAGE(buf, ch)                                                          \
    {                                                                           \
        const int kv0_ = (ch) * 64;                                             \
        _Pragma("unroll")                                                       \
        for (int i_ = 0; i_ < 2; ++i_) {                                        \
            int slot_ = i_ * 4 + wg;                                            \
            int r_ = slot_ * 8 + lr;                                            \
            gload16(&Kh[(size_t)(kv0_ + r_) * 64 + lc * 8],                     \
                    &Ks[grp][buf][slot_ * 512 + lane * 8]);                     \
            gload16(&Vh[(size_t)r_ * Tn + kv0_ + lc * 8],                       \
                    &Vs[grp][buf][slot_ * 512 + lane * 8]);                     \
        }                                                                       \
    }

    if (nmy > 0) STAGE(0, chbase);                   // 4 loads in flight

    for (int i = 0; i < mid; ++i) {                  // barrier-uniform loop
        const bool valid = i < nmy;
        const int ch = chbase + i;
        const int kv0 = ch * 64;
        const int cur = i & 1;
        if (valid) {
            if (i + 1 < nmy) {
                STAGE((i + 1) & 1, ch + 1);          // +4 -> 8 in flight
                asm volatile("s_waitcnt vmcnt(4)" ::: "memory");  // cur landed
            } else {
                asm volatile("s_waitcnt vmcnt(0)" ::: "memory");
            }
        }
        __builtin_amdgcn_s_barrier();                // raw: no vmcnt(0) drain
        asm volatile("" ::: "memory");

        if (valid) {
            // ---- S^T = K·Q : 4 key-subtiles ----
            f32x4 sacc[4];
            __builtin_amdgcn_s_setprio(1);
#pragma unroll
            for (int sub = 0; sub < 4; ++sub) {
                const int krow = sub * 16 + qi;
                s16x8 ka = *(const s16x8*)&Ks[grp][cur][krow * 64 + ((g ^ (qi & 7))) * 8];
                s16x8 kc = *(const s16x8*)&Ks[grp][cur][krow * 64 + (((4 | g) ^ (qi & 7))) * 8];
                f32x4 t0 = __builtin_amdgcn_mfma_f32_16x16x32_bf16(ka, qf[0], z4, 0, 0, 0);
                sacc[sub] = __builtin_amdgcn_mfma_f32_16x16x32_bf16(kc, qf[1], t0, 0, 0, 0);
            }
            __builtin_amdgcn_s_setprio(0);

            // ---- P = exp2(S) (Q pre-scaled), partial l, bf16 fragments ----
            float pe[16];
            if (kv0 + 63 <= wrow0) {                 // interior: no masking
#pragma unroll
                for (int e2 = 0; e2 < 16; ++e2)
                    pe[e2] = exp2f(sacc[e2 >> 2][e2 & 3]);
            } else {
                const int qrow = wrow0 + qi;
#pragma unroll
                for (int sub = 0; sub < 4; ++sub)
#pragma unroll
                    for (int r = 0; r < 4; ++r) {
                        int key = kv0 + sub * 16 + 4 * g + r;
                        pe[sub * 4 + r] = (key <= qrow) ? exp2f(sacc[sub][r]) : 0.f;
                    }
            }
            {   // tree sum into per-lane partial
                float a0 = (pe[0] + pe[1]) + (pe[2] + pe[3]);
                float a1 = (pe[4] + pe[5]) + (pe[6] + pe[7]);
                float a2 = (pe[8] + pe[9]) + (pe[10] + pe[11]);
                float a3 = (pe[12] + pe[13]) + (pe[14] + pe[15]);
                lsum += (a0 + a1) + (a2 + a3);
            }
            s16x8 pf[2];
#pragma unroll
            for (int c = 0; c < 2; ++c)
#pragma unroll
                for (int e2 = 0; e2 < 8; ++e2) pf[c][e2] = f2bs(pe[c * 8 + e2]);

            // ---- O += P·V ----
            __builtin_amdgcn_s_setprio(1);
#pragma unroll
            for (int c = 0; c < 2; ++c)
#pragma unroll
                for (int dt = 0; dt < 4; ++dt) {
                    const int vrow = dt * 16 + qi;
                    s16x8 vf = *(const s16x8*)&Vs[grp][cur][vrow * 64 +
                                                   ((((c << 2) | g) ^ (qi & 7))) * 8];
                    O[dt] = __builtin_amdgcn_mfma_f32_16x16x32_bf16(
                        pf[c], vf, O[dt], 0, 0, 0);
                }
            __builtin_amdgcn_s_setprio(0);
        }
        asm volatile("" ::: "memory");
        __builtin_amdgcn_s_barrier();                // raw: protect cur buffer
        asm volatile("" ::: "memory");
    }
#undef STAGE

    // ---- cross-lane l reduce (every lane holds its qi's group-total) ----
    lsum += __shfl_xor(lsum, 16);
    lsum += __shfl_xor(lsum, 32);

    // ---- in-block merge: group B publishes into LDS scratch, group A sums ----
    f32x4* Osc = (f32x4*)&Ks[0][0][0];               // 16KB scratch (reuse K LDS)
    float* Lsc = (float*)&Vs[0][0][0];               // 64 floats (reuse V LDS)
    __syncthreads();                                 // all loads/reads done
    if (grp == 1) {
#pragma unroll
        for (int dt = 0; dt < 4; ++dt)
            Osc[(dt * 4 + wg) * 64 + lane] = O[dt];  // lane-consecutive f32x4
        if (g == 0) Lsc[wg * 16 + qi] = lsum;
    }
    __syncthreads();
    if (grp == 0) {
        float lt = lsum + Lsc[wg * 16 + qi];
#pragma unroll
        for (int dt = 0; dt < 4; ++dt) {
            f32x4 p = Osc[(dt * 4 + wg) * 64 + lane];
            O[dt][0] += p[0]; O[dt][1] += p[1]; O[dt][2] += p[2]; O[dt][3] += p[3];
        }
#pragma unroll
        for (int r = 0; r < 4; ++r) {
            float li = __shfl(lt, 4 * g + r);
            float inv = 1.f / li;
            int t = wrow0 + 4 * g + r;
#pragma unroll
            for (int dt = 0; dt < 4; ++dt)
                AO[((size_t)(b * Tn + t)) * Cn + h * 64 + dt * 16 + qi] =
                    f2bs(O[dt][r] * inv);
        }
    }
}

// ---------------- launcher (4 dispatches) ----------------

extern "C" void kernel_launch(void* const* d_in, const int* in_sizes, int n_in,
                              void* d_out, int out_size, void* d_ws, size_t ws_size,
                              hipStream_t stream) {
    const float* x = (const float*)d_in[0];
    const float* Wqkv = (const float*)d_in[1];
    const float* Wproj = (const float*)d_in[2];
    float* out = (float*)d_out;

    char* ws = (char*)d_ws;
    size_t o = 0;
    short* xb = (short*)(ws + o);      o += (size_t)BT * Cn * 2;            // 8MB (AO alias)
    short* wqkvT = (short*)(ws + o);   o += (size_t)NQKV * Cn * 2;          // 1.5MB
    short* wprojT = (short*)(ws + o);  o += (size_t)Cn * Cn * 2;            // 0.5MB
    short* Qb = (short*)(ws + o);      o += (size_t)Bn * Hn * Tn * Dn * 2;  // 8MB
    short* Kb = (short*)(ws + o);      o += (size_t)Bn * Hn * Tn * Dn * 2;  // 8MB
    short* Vt = (short*)(ws + o);      o += (size_t)Bn * Hn * Tn * Dn * 2;  // 8MB
    float2* csT = (float2*)(ws + o);   o += (size_t)Tn * Dn * 8;            // 1MB

    k_prep<<<dim3(4864), 256, 0, stream>>>(x, Wqkv, Wproj, xb, wqkvT, wprojT, csT);

    gemm_kernel<0, 4><<<dim3(NQKV / 128, BT / 128), 256, 0, stream>>>(
        xb, wqkvT, csT, Qb, Kb, Vt, nullptr);

    attn_kernel<<<dim3(1024), 512, 0, stream>>>(Qb, Kb, Vt, xb /*AO alias*/);

    gemm_kernel<1, 2><<<dim3(Cn / 64, BT / 128), 256, 0, stream>>>(
        xb /*AO*/, wprojT, csT, nullptr, nullptr, nullptr, out);
}

// Round 22
// 80.780 us; speedup vs baseline: 1.0341x; 1.0341x over previous
//
#include <hip/hip_runtime.h>
#include <hip/hip_bf16.h>
#include <stdint.h>

// Problem constants (B=4, T=2048, C=512, H=8, D=64)
constexpr int Bn = 4;
constexpr int Tn = 2048;
constexpr int Cn = 512;
constexpr int Hn = 8;
constexpr int Dn = 64;
constexpr int BT = Bn * Tn;          // 8192
constexpr int NQKV = 3 * Cn;         // 1536

typedef __attribute__((ext_vector_type(4))) float  f32x4;
typedef __attribute__((ext_vector_type(8))) short  s16x8;
typedef __attribute__((ext_vector_type(4))) short  s16x4;

__device__ __forceinline__ short f2bs(float f) {
    __hip_bfloat16 h = __float2bfloat16(f);
    return *reinterpret_cast<short*>(&h);
}

// async global->LDS, 16B per lane (linear LDS dest: wave base + lane*16)
__device__ __forceinline__ void gload16(const short* g, short* l) {
    __builtin_amdgcn_global_load_lds(
        (const __attribute__((address_space(1))) void*)g,
        (__attribute__((address_space(3))) void*)l, 16, 0, 0);
}

// ---------------- fused prep kernel ----------------
// blocks [0,4096): x fp32 -> bf16          (job A)
// blocks [4096,4352): weight transposes    (job B)
// blocks [4352,4864): rope cos/sin table   (job C)

__global__ __launch_bounds__(256) void k_prep(const float* __restrict__ x,
                                              const float* __restrict__ Wqkv,
                                              const float* __restrict__ Wproj,
                                              short* __restrict__ xb,
                                              short* __restrict__ wqkvT,
                                              short* __restrict__ wprojT,
                                              float2* __restrict__ csT) {
    const int bid = blockIdx.x;
    const int tid = threadIdx.x;
    __shared__ float lds[64 * 65];

    if (bid < 4096) {                        // A: conv x (float4 per thread)
        int i = bid * 256 + tid;
        f32x4 v = reinterpret_cast<const f32x4*>(x)[i];
        s16x4 o;
        o[0] = f2bs(v[0]); o[1] = f2bs(v[1]); o[2] = f2bs(v[2]); o[3] = f2bs(v[3]);
        reinterpret_cast<s16x4*>(xb)[i] = o;
    } else if (bid < 4352) {                 // B: weight transpose via LDS tile
        int wb = bid - 4096;
        const float* W; short* out; int N, n0, k0;
        if (wb < 192) {
            W = Wqkv; out = wqkvT; N = NQKV;
            n0 = (wb >> 3) * 64; k0 = (wb & 7) * 64;
        } else {
            wb -= 192;
            W = Wproj; out = wprojT; N = Cn;
            n0 = (wb >> 3) * 64; k0 = (wb & 7) * 64;
        }
#pragma unroll
        for (int i = 0; i < 16; ++i) {
            int flat = i * 256 + tid;
            int k = flat >> 6, n = flat & 63;
            lds[n * 65 + k] = W[(size_t)(k0 + k) * N + n0 + n];
        }
        __syncthreads();
#pragma unroll
        for (int i = 0; i < 16; ++i) {
            int flat = i * 256 + tid;
            int n = flat >> 6, k = flat & 63;
            out[(size_t)(n0 + n) * 512 + k0 + k] = f2bs(lds[n * 65 + k]);
        }
    } else {                                 // C: rope table
        int i = (bid - 4352) * 256 + tid;    // < T*D
        int t = i >> 6, d = i & 63;
        float inv = exp2f(-(float)(d & 31) * 0.41524101186f);
        float fr = (float)t * inv;
        csT[i] = make_float2(cosf(fr), sinf(fr));
    }
}

// ---------------- GEMM (128x128 tile, BK=32, 4 blocks/CU, counted vmcnt) ------
// (r19 structure, the measured optimum: −6.3us vs BK=64)

template <int MODE>
__global__ __launch_bounds__(256, 4) void gemm_kernel(
    const short* __restrict__ A, const short* __restrict__ Bt,
    const float2* __restrict__ csT,
    short* __restrict__ Qb, short* __restrict__ Kb, short* __restrict__ Vt,
    float* __restrict__ outF) {
    const int m0 = blockIdx.y * 128;
    const int n0 = blockIdx.x * 128;
    const int tid = threadIdx.x;
    const int w = tid >> 6, lane = tid & 63;
    const int qi = lane & 15, g = lane >> 4;
    const int wr = w >> 1, wc = w & 1;

    __shared__ short As[2][128 * 32];
    __shared__ short Bs[2][128 * 32];

    f32x4 acc[4][4];
#pragma unroll
    for (int mt = 0; mt < 4; ++mt)
#pragma unroll
        for (int nt = 0; nt < 4; ++nt) acc[mt][nt] = (f32x4){0.f, 0.f, 0.f, 0.f};

    const int lrr = lane >> 2;          // sub-row within 16-row slab
    const int lp = lane & 3;            // stored chunk position

#define STAGEG(buf, k0)                                                         \
    {                                                                           \
        _Pragma("unroll")                                                       \
        for (int i_ = 0; i_ < 2; ++i_) {                                        \
            int row_ = i_ * 64 + w * 16 + lrr;                                  \
            int c_ = lp ^ ((row_ ^ (row_ >> 2)) & 3);                           \
            gload16(&A[(size_t)(m0 + row_) * 512 + (k0) + c_ * 8],              \
                    &As[buf][(i_ * 64 + w * 16) * 32 + lane * 8]);              \
            gload16(&Bt[(size_t)(n0 + row_) * 512 + (k0) + c_ * 8],             \
                    &Bs[buf][(i_ * 64 + w * 16) * 32 + lane * 8]);              \
        }                                                                       \
    }

    STAGEG(0, 0);                                    // 4 loads in flight

    for (int it = 0; it < 16; ++it) {                // K = 16 * 32
        const int cur = it & 1;
        if (it + 1 < 16) {
            STAGEG((it + 1) & 1, (it + 1) * 32);     // +4 -> 8 in flight
            asm volatile("s_waitcnt vmcnt(4)" ::: "memory");   // cur landed
        } else {
            asm volatile("s_waitcnt vmcnt(0)" ::: "memory");
        }
        __builtin_amdgcn_s_barrier();
        asm volatile("" ::: "memory");

        s16x8 af[4], bf[4];
#pragma unroll
        for (int mt = 0; mt < 4; ++mt) {
            int row = wr * 64 + mt * 16 + qi;
            int p = g ^ ((row ^ (row >> 2)) & 3);
            af[mt] = *(const s16x8*)&As[cur][row * 32 + p * 8];
        }
#pragma unroll
        for (int nt = 0; nt < 4; ++nt) {
            int row = wc * 64 + nt * 16 + qi;
            int p = g ^ ((row ^ (row >> 2)) & 3);
            bf[nt] = *(const s16x8*)&Bs[cur][row * 32 + p * 8];
        }
#pragma unroll
        for (int mt = 0; mt < 4; ++mt)
#pragma unroll
            for (int nt = 0; nt < 4; ++nt)
                acc[mt][nt] = __builtin_amdgcn_mfma_f32_16x16x32_bf16(
                    af[mt], bf[nt], acc[mt][nt], 0, 0, 0);

        asm volatile("" ::: "memory");
        __builtin_amdgcn_s_barrier();
        asm volatile("" ::: "memory");
    }
#undef STAGEG

    if (MODE == 1) {
#pragma unroll
        for (int mt = 0; mt < 4; ++mt)
#pragma unroll
            for (int nt = 0; nt < 4; ++nt)
#pragma unroll
                for (int r = 0; r < 4; ++r)
                    outF[(size_t)(m0 + wr * 64 + mt * 16 + 4 * g + r) * 512 +
                         n0 + wc * 64 + nt * 16 + qi] = acc[mt][nt][r];
    } else {
        const int seg64 = (n0 >> 6) + wc;            // = h*3 + seg
        const int h = seg64 / 3;
        const int seg = seg64 % 3;                   // 0=q 1=k 2=v
        const int b = m0 >> 11;
        const int tb = (m0 & 2047) + wr * 64;
        const float QSC = 0.125f * 1.44269504f;      // pre-fold softmax scale into Q
        if (seg == 2) {
            // V transposed + fragment-permuted: Vt[bh][d][ (t&~31) + g2*8 + sub2*4 + r2 ]
            const size_t vbase = (size_t)(b * Hn + h) * Dn;
#pragma unroll
            for (int mt = 0; mt < 4; ++mt)
#pragma unroll
                for (int nt = 0; nt < 4; ++nt)
#pragma unroll
                    for (int r = 0; r < 4; ++r) {
                        int t = tb + mt * 16 + 4 * g + r;
                        int d = nt * 16 + qi;
                        int o = t & 31;
                        int jj = (t & ~31) + ((o >> 2) & 3) * 8 + (o >> 4) * 4 + (o & 3);
                        Vt[(vbase + d) * Tn + jj] = f2bs(acc[mt][nt][r]);
                    }
        } else {
            short* dst = (seg == 0) ? Qb : Kb;
            const float post = (seg == 0) ? QSC : 1.0f;
            const size_t headbase = (size_t)(b * Hn + h) * Tn;
#pragma unroll
            for (int mt = 0; mt < 4; ++mt)
#pragma unroll
                for (int nt = 0; nt < 4; ++nt)
#pragma unroll
                    for (int r = 0; r < 4; ++r) {
                        int t = tb + mt * 16 + 4 * g + r;
                        int d = nt * 16 + qi;
                        float val = acc[mt][nt][r];
                        float pv = (nt < 2) ? -acc[mt][nt + 2][r] : acc[mt][nt - 2][r];
                        float2 cs = csT[t * 64 + d];
                        dst[(headbase + t) * Dn + d] = f2bs((val * cs.x + pv * cs.y) * post);
                    }
        }
    }
}

// ---------------- causal flash attention (IN-BLOCK split-K, 8 waves) -----------
// (r18 structure verbatim — proven best of 7 attn variants)

__global__ __launch_bounds__(512, 4) void attn_kernel(const short* __restrict__ Qb,
                                                      const short* __restrict__ Kb,
                                                      const short* __restrict__ Vt,
                                                      short* __restrict__ AO) {
    const int idx = blockIdx.x;
    const int bh = idx & 31;
    const int qt = 31 - (idx >> 5);                  // heavy tiles dispatch first
    const int q0 = qt * 64;
    const int tid = threadIdx.x;
    const int w = tid >> 6, lane = tid & 63;
    const int qi = lane & 15, g = lane >> 4;
    const int grp = w >> 2;                          // chunk-range group
    const int wg = w & 3;                            // wave-in-group (16 rows)
    const int b = bh >> 3, h = bh & 7;

    __shared__ short Ks[2][2][64 * 64];  // [grp][dbuf][key][d]     32KB
    __shared__ short Vs[2][2][64 * 64];  // [grp][dbuf][d][key-perm] 32KB

    const short* Qh = Qb + (size_t)bh * Tn * Dn;
    const short* Kh = Kb + (size_t)bh * Tn * Dn;
    const short* Vh = Vt + (size_t)bh * Dn * Tn;

    const int wrow0 = q0 + wg * 16;      // wave's 16 query rows
    s16x8 qf[2];
#pragma unroll
    for (int dh = 0; dh < 2; ++dh)
        qf[dh] = *(const s16x8*)&Qh[(size_t)(wrow0 + qi) * Dn + dh * 32 + g * 8];

    f32x4 O[4];
#pragma unroll
    for (int dt = 0; dt < 4; ++dt) O[dt] = (f32x4){0.f, 0.f, 0.f, 0.f};
    float lsum = 0.f;

    const int nch = qt + 1;                          // 64-key chunks total
    const int mid = (nch + 1) >> 1;                  // group A: [0,mid)
    const int chbase = grp ? mid : 0;
    const int nmy = grp ? (nch - mid) : mid;         // my group's chunk count
    const f32x4 z4 = {0.f, 0.f, 0.f, 0.f};

    const int lr = lane >> 3;                        // staging sub-row
    const int lc = (lane & 7) ^ lr;                  // pre-swizzled global chunk

#define STAGE(buf, ch)                                                          \
    {                                                                           \
        const int kv0_ = (ch) * 64;                                             \
        _Pragma("unroll")                                                       \
        for (int i_ = 0; i_ < 2; ++i_) {                                        \
            int slot_ = i_ * 4 + wg;                                            \
            int r_ = slot_ * 8 + lr;                                            \
            gload16(&Kh[(size_t)(kv0_ + r_) * 64 + lc * 8],                     \
                    &Ks[grp][buf][slot_ * 512 + lane * 8]);                     \
            gload16(&Vh[(size_t)r_ * Tn + kv0_ + lc * 8],                       \
                    &Vs[grp][buf][slot_ * 512 + lane * 8]);                     \
        }                                                                       \
    }

    if (nmy > 0) STAGE(0, chbase);                   // 4 loads in flight

    for (int i = 0; i < mid; ++i) {                  // barrier-uniform loop
        const bool valid = i < nmy;
        const int ch = chbase + i;
        const int kv0 = ch * 64;
        const int cur = i & 1;
        if (valid) {
            if (i + 1 < nmy) {
                STAGE((i + 1) & 1, ch + 1);          // +4 -> 8 in flight
                asm volatile("s_waitcnt vmcnt(4)" ::: "memory");  // cur landed
            } else {
                asm volatile("s_waitcnt vmcnt(0)" ::: "memory");
            }
        }
        __builtin_amdgcn_s_barrier();                // raw: no vmcnt(0) drain
        asm volatile("" ::: "memory");

        if (valid) {
            // ---- S^T = K·Q : 4 key-subtiles ----
            f32x4 sacc[4];
            __builtin_amdgcn_s_setprio(1);
#pragma unroll
            for (int sub = 0; sub < 4; ++sub) {
                const int krow = sub * 16 + qi;
                s16x8 ka = *(const s16x8*)&Ks[grp][cur][krow * 64 + ((g ^ (qi & 7))) * 8];
                s16x8 kc = *(const s16x8*)&Ks[grp][cur][krow * 64 + (((4 | g) ^ (qi & 7))) * 8];
                f32x4 t0 = __builtin_amdgcn_mfma_f32_16x16x32_bf16(ka, qf[0], z4, 0, 0, 0);
                sacc[sub] = __builtin_amdgcn_mfma_f32_16x16x32_bf16(kc, qf[1], t0, 0, 0, 0);
            }
            __builtin_amdgcn_s_setprio(0);

            // ---- P = exp2(S) (Q pre-scaled), partial l, bf16 fragments ----
            float pe[16];
            if (kv0 + 63 <= wrow0) {                 // interior: no masking
#pragma unroll
                for (int e2 = 0; e2 < 16; ++e2)
                    pe[e2] = exp2f(sacc[e2 >> 2][e2 & 3]);
            } else {
                const int qrow = wrow0 + qi;
#pragma unroll
                for (int sub = 0; sub < 4; ++sub)
#pragma unroll
                    for (int r = 0; r < 4; ++r) {
                        int key = kv0 + sub * 16 + 4 * g + r;
                        pe[sub * 4 + r] = (key <= qrow) ? exp2f(sacc[sub][r]) : 0.f;
                    }
            }
            {   // tree sum into per-lane partial
                float a0 = (pe[0] + pe[1]) + (pe[2] + pe[3]);
                float a1 = (pe[4] + pe[5]) + (pe[6] + pe[7]);
                float a2 = (pe[8] + pe[9]) + (pe[10] + pe[11]);
                float a3 = (pe[12] + pe[13]) + (pe[14] + pe[15]);
                lsum += (a0 + a1) + (a2 + a3);
            }
            s16x8 pf[2];
#pragma unroll
            for (int c = 0; c < 2; ++c)
#pragma unroll
                for (int e2 = 0; e2 < 8; ++e2) pf[c][e2] = f2bs(pe[c * 8 + e2]);

            // ---- O += P·V ----
            __builtin_amdgcn_s_setprio(1);
#pragma unroll
            for (int c = 0; c < 2; ++c)
#pragma unroll
                for (int dt = 0; dt < 4; ++dt) {
                    const int vrow = dt * 16 + qi;
                    s16x8 vf = *(const s16x8*)&Vs[grp][cur][vrow * 64 +
                                                   ((((c << 2) | g) ^ (qi & 7))) * 8];
                    O[dt] = __builtin_amdgcn_mfma_f32_16x16x32_bf16(
                        pf[c], vf, O[dt], 0, 0, 0);
                }
            __builtin_amdgcn_s_setprio(0);
        }
        asm volatile("" ::: "memory");
        __builtin_amdgcn_s_barrier();                // raw: protect cur buffer
        asm volatile("" ::: "memory");
    }
#undef STAGE

    // ---- cross-lane l reduce (every lane holds its qi's group-total) ----
    lsum += __shfl_xor(lsum, 16);
    lsum += __shfl_xor(lsum, 32);

    // ---- in-block merge: group B publishes into LDS scratch, group A sums ----
    f32x4* Osc = (f32x4*)&Ks[0][0][0];               // 16KB scratch (reuse K LDS)
    float* Lsc = (float*)&Vs[0][0][0];               // 64 floats (reuse V LDS)
    __syncthreads();                                 // all loads/reads done
    if (grp == 1) {
#pragma unroll
        for (int dt = 0; dt < 4; ++dt)
            Osc[(dt * 4 + wg) * 64 + lane] = O[dt];  // lane-consecutive f32x4
        if (g == 0) Lsc[wg * 16 + qi] = lsum;
    }
    __syncthreads();
    if (grp == 0) {
        float lt = lsum + Lsc[wg * 16 + qi];
#pragma unroll
        for (int dt = 0; dt < 4; ++dt) {
            f32x4 p = Osc[(dt * 4 + wg) * 64 + lane];
            O[dt][0] += p[0]; O[dt][1] += p[1]; O[dt][2] += p[2]; O[dt][3] += p[3];
        }
#pragma unroll
        for (int r = 0; r < 4; ++r) {
            float li = __shfl(lt, 4 * g + r);
            float inv = 1.f / li;
            int t = wrow0 + 4 * g + r;
#pragma unroll
            for (int dt = 0; dt < 4; ++dt)
                AO[((size_t)(b * Tn + t)) * Cn + h * 64 + dt * 16 + qi] =
                    f2bs(O[dt][r] * inv);
        }
    }
}

// ---------------- launcher (4 dispatches) ----------------

extern "C" void kernel_launch(void* const* d_in, const int* in_sizes, int n_in,
                              void* d_out, int out_size, void* d_ws, size_t ws_size,
                              hipStream_t stream) {
    const float* x = (const float*)d_in[0];
    const float* Wqkv = (const float*)d_in[1];
    const float* Wproj = (const float*)d_in[2];
    float* out = (float*)d_out;

    char* ws = (char*)d_ws;
    size_t o = 0;
    short* xb = (short*)(ws + o);      o += (size_t)BT * Cn * 2;            // 8MB (AO alias)
    short* wqkvT = (short*)(ws + o);   o += (size_t)NQKV * Cn * 2;          // 1.5MB
    short* wprojT = (short*)(ws + o);  o += (size_t)Cn * Cn * 2;            // 0.5MB
    short* Qb = (short*)(ws + o);      o += (size_t)Bn * Hn * Tn * Dn * 2;  // 8MB
    short* Kb = (short*)(ws + o);      o += (size_t)Bn * Hn * Tn * Dn * 2;  // 8MB
    short* Vt = (short*)(ws + o);      o += (size_t)Bn * Hn * Tn * Dn * 2;  // 8MB
    float2* csT = (float2*)(ws + o);   o += (size_t)Tn * Dn * 8;            // 1MB

    k_prep<<<dim3(4864), 256, 0, stream>>>(x, Wqkv, Wproj, xb, wqkvT, wprojT, csT);

    gemm_kernel<0><<<dim3(NQKV / 128, BT / 128), 256, 0, stream>>>(
        xb, wqkvT, csT, Qb, Kb, Vt, nullptr);

    attn_kernel<<<dim3(1024), 512, 0, stream>>>(Qb, Kb, Vt, xb /*AO alias*/);

    gemm_kernel<1><<<dim3(Cn / 128, BT / 128), 256, 0, stream>>>(
        xb /*AO*/, wprojT, csT, nullptr, nullptr, nullptr, out);
}